// Round 1
// 206.783 us; speedup vs baseline: 1.0813x; 1.0813x over previous
//
#include <hip/hip_runtime.h>
#include <cstdint>
#include <math.h>

#define B2v 4
#define Cc  128
#define Hh  64
#define Ww  256
#define Gg  8
#define Pp  4
#define HW  (Hh*Ww)      // 16384
#define CHW (Cc*HW)      // 2097152
#define PIT 136          // LDS tile pitch in bf16 elems (272 B, 16B-aligned rows)

typedef float f32x4 __attribute__((ext_vector_type(4)));
typedef float f32x2 __attribute__((ext_vector_type(2)));
typedef short s16x8 __attribute__((ext_vector_type(8)));
typedef short s16x4 __attribute__((ext_vector_type(4)));

__device__ __forceinline__ short f2bf(float x) {
    union { float f; unsigned u; } a; a.f = x;
    unsigned r = a.u + 0x7fffu + ((a.u >> 16) & 1u);   // RNE
    return (short)(r >> 16);
}
__device__ __forceinline__ float bf2f(short s) {
    union { unsigned u; float f; } a; a.u = ((unsigned)(unsigned short)s) << 16;
    return a.f;
}
// 2x f32 -> packed bf16x2 in one VALU op (no builtin on gfx950; guide T12 recipe)
__device__ __forceinline__ unsigned cvtpk(float lo, float hi) {
    unsigned r;
    asm("v_cvt_pk_bf16_f32 %0, %1, %2" : "=v"(r) : "v"(lo), "v"(hi));
    return r;
}
// packed bf16x2 -> 2x f32 (1 shift + 1 and)
__device__ __forceinline__ f32x2 unpk(unsigned w) {
    union { unsigned u; float f; } lo, hi;
    lo.u = w << 16; hi.u = w & 0xffff0000u;
    return (f32x2){lo.f, hi.f};
}
__device__ __forceinline__ float frcp(float x) { return __builtin_amdgcn_rcpf(x); }
__device__ __forceinline__ float fexp(float x) { return __expf(x); }

// ---------------------------------------------------------------------------
// Kernel 0: weights f32 -> bf16.
// [0,16384) wv | [16384,32768) wq=[woc;wog;wa] | [32768,49152) wo
// [49152,81920) w1 | [81920,114688) w2 ; bq[128]=[boc;bog;ba] f32
// ---------------------------------------------------------------------------
__global__ __launch_bounds__(256) void prep_kernel(
    const float* __restrict__ wv, const float* __restrict__ woc,
    const float* __restrict__ wog, const float* __restrict__ wa,
    const float* __restrict__ wo, const float* __restrict__ w1,
    const float* __restrict__ w2,
    const float* __restrict__ boc, const float* __restrict__ bog,
    const float* __restrict__ ba,
    short* __restrict__ wbf, float* __restrict__ bq)
{
    int i = blockIdx.x * 256 + threadIdx.x;
    if (i < 16384) wbf[i] = f2bf(wv[i]);
    else if (i < 32768) {
        int j = i - 16384; int r = j >> 7, c = j & 127;
        float v = (r < 32) ? woc[r * 128 + c] : (r < 64) ? wog[(r - 32) * 128 + c]
                                              : wa[(r - 64) * 128 + c];
        wbf[i] = f2bf(v);
    }
    else if (i < 49152)  wbf[i] = f2bf(wo[i - 32768]);
    else if (i < 81920)  wbf[i] = f2bf(w1[i - 49152]);
    else if (i < 114688) wbf[i] = f2bf(w2[i - 81920]);
    else if (i < 114816) {
        int r = i - 114688;
        bq[r] = (r < 32) ? boc[r] : (r < 64) ? bog[r - 32] : ba[r - 64];
    }
}

// ---------------------------------------------------------------------------
// Mega kernel: whole block per output row (b,h). 512 threads (8 waves).
// Buffer choreography (one barrier per arrow):
//   P0 stage ctx->buf1, q->buf2 (single merged HBM burst, dwordx4 loads)
//   P1 value MFMA (buf1->regs) | P2 pack value->buf1 + proj MFMA (buf2->regs)
//   P3 pack proj->buf2 | P4 softmax/keypoints (regs) | P5 sampling->agg buf2
//   P6 out-proj MFMA (buf2) + pack x->buf1 (no inner barrier: disjoint bufs)
//   P7 LayerNorm in buf1 | P8 FFN (buf1 -> hidden buf2 -> acc) | store
// ---------------------------------------------------------------------------
__global__ __launch_bounds__(512, 2) void mega_kernel(
    const float* __restrict__ mlq, const float* __restrict__ mrq,
    const float* __restrict__ fl,  const float* __restrict__ fr,
    const float* __restrict__ nl,  const float* __restrict__ nr,
    const float* __restrict__ gml, const float* __restrict__ gmr,
    const float* __restrict__ cap, const float* __restrict__ gap,
    const short* __restrict__ wbf, const float* __restrict__ bq,
    const float* __restrict__ bv,
    const float* __restrict__ wn,  const float* __restrict__ bn,
    const float* __restrict__ bo,
    const float* __restrict__ lnw, const float* __restrict__ lnb,
    const float* __restrict__ b1,  const float* __restrict__ b2,
    float* __restrict__ out_ml, float* __restrict__ out_mr,
    float* __restrict__ ckp_out, float* __restrict__ gkp_out)
{
    __shared__ short buf1[256 * PIT];   // ctx -> value -> x/xn
    __shared__ short buf2[256 * PIT];   // q -> proj -> agg -> ffn hidden
    __shared__ f32x4 sgeo4[256];        // (g0,g1,g2,0) per pixel: one b128 gather
    __shared__ f32x2 swnp[256];         // [ch-pair][comp0..3] of (wn|bn)
    __shared__ float sln[256];          // lnw[128] ; lnb[128]
    __shared__ float redS[512], redQ[512];
    __shared__ float smu[256], srs[256];

    const short* wv_bf = wbf;
    const short* wq_bf = wbf + 16384;
    const short* wo_bf = wbf + 32768;
    const short* w1_bf = wbf + 49152;
    const short* w2_bf = wbf + 81920;

    const int t    = threadIdx.x;
    const int lane = t & 63;
    const int ww   = t >> 6;          // wave 0..7
    const int lm   = lane & 15;
    const int lq   = lane >> 4;
    const int h = blockIdx.x, b = blockIdx.y;
    const int hWw = h * Ww;
    const int px   = t & 255;         // per-pixel phases
    const int half = t >> 8;          // 0/1 (channel/group half)

    const float* ctx = (b < 2) ? fr + (size_t)b * CHW : fl + (size_t)(b - 2) * CHW;
    const float* q   = (b < 2) ? mlq + (size_t)b * CHW : mrq + (size_t)(b - 2) * CHW;
    const float* geo = (b < 2) ? nr + (size_t)b * 3 * HW : nl + (size_t)(b - 2) * 3 * HW;
    const float* msk = (b < 2) ? gml + (size_t)b * HW : gmr + (size_t)(b - 2) * HW;
    float* outp = (b < 2) ? out_ml + (size_t)b * CHW : out_mr + (size_t)(b - 2) * CHW;

    // ---- prefetch cap/gap anchors into regs (consumed in P4; 5 phases of cover)
    float capr[16], gapr[16];
    const size_t kbase = ((size_t)b * Gg + half * 4) * Pp * (size_t)HW + hWw + px;
    {
#pragma unroll
        for (int i = 0; i < 16; i++) {
            capr[i] = cap[kbase + (size_t)i * HW];
            gapr[i] = gap[kbase + (size_t)i * HW];
        }
    }

    // ---- small constants (consumed after later barriers)
    if (t < 256) {
        sgeo4[t] = (f32x4){geo[hWw + t], geo[HW + hWw + t], geo[2 * HW + hWw + t], 0.f};
        const int pr = t >> 2, m = t & 3;
        const int ch0 = pr * 2, ch1 = ch0 + 1;
        float a0 = (m < 3) ? wn[ch0 * 3 + m] : bn[ch0];
        float a1 = (m < 3) ? wn[ch1 * 3 + m] : bn[ch1];
        swnp[t] = (f32x2){a0, a1};
    }
    else {
        int i = t - 256;   // 0..255
        sln[i] = (i < 128) ? lnw[i] : lnb[i - 128];
    }

    // ---- P0: stage ctx -> buf1 and q -> buf2 (dwordx4 loads, b128 LDS writes)
    {
        const int c0 = ww * 16;
        const int p0 = lane * 4;
        const size_t gbase = (size_t)c0 * HW + hWw + p0;
        {
            f32x4 L[16];
#pragma unroll
            for (int c = 0; c < 16; c++) L[c] = *(const f32x4*)(ctx + gbase + (size_t)c * HW);
#pragma unroll
            for (int j = 0; j < 4; j++) {
                uint4 w0, w1;
                w0.x = cvtpk(L[0][j],  L[1][j]);  w0.y = cvtpk(L[2][j],  L[3][j]);
                w0.z = cvtpk(L[4][j],  L[5][j]);  w0.w = cvtpk(L[6][j],  L[7][j]);
                w1.x = cvtpk(L[8][j],  L[9][j]);  w1.y = cvtpk(L[10][j], L[11][j]);
                w1.z = cvtpk(L[12][j], L[13][j]); w1.w = cvtpk(L[14][j], L[15][j]);
                *(uint4*)(&buf1[(p0 + j) * PIT + c0])     = w0;
                *(uint4*)(&buf1[(p0 + j) * PIT + c0 + 8]) = w1;
            }
        }
        {
            f32x4 L[16];
#pragma unroll
            for (int c = 0; c < 16; c++) L[c] = *(const f32x4*)(q + gbase + (size_t)c * HW);
#pragma unroll
            for (int j = 0; j < 4; j++) {
                uint4 w0, w1;
                w0.x = cvtpk(L[0][j],  L[1][j]);  w0.y = cvtpk(L[2][j],  L[3][j]);
                w0.z = cvtpk(L[4][j],  L[5][j]);  w0.w = cvtpk(L[6][j],  L[7][j]);
                w1.x = cvtpk(L[8][j],  L[9][j]);  w1.y = cvtpk(L[10][j], L[11][j]);
                w1.z = cvtpk(L[12][j], L[13][j]); w1.w = cvtpk(L[14][j], L[15][j]);
                *(uint4*)(&buf2[(p0 + j) * PIT + c0])     = w0;
                *(uint4*)(&buf2[(p0 + j) * PIT + c0 + 8]) = w1;
            }
        }
    }
    __syncthreads();

    // ---- P1: value = wv @ ctx (buf1) -> regs
    f32x4 accv[16];
#pragma unroll
    for (int nt = 0; nt < 16; nt++) accv[nt] = (f32x4){0.f, 0.f, 0.f, 0.f};
#pragma unroll
    for (int kk = 0; kk < 4; kk++) {
        s16x8 a = *(const s16x8*)(wv_bf + (size_t)(ww * 16 + lm) * 128 + kk * 32 + lq * 8);
#pragma unroll
        for (int nt = 0; nt < 16; nt++) {
            s16x8 bfv = *(const s16x8*)(&buf1[(nt * 16 + lm) * PIT + kk * 32 + lq * 8]);
            accv[nt] = __builtin_amdgcn_mfma_f32_16x16x32_bf16(a, bfv, accv[nt], 0, 0, 0);
        }
    }
    __syncthreads();   // all ctx reads done; buf1 reusable for value

    // ---- P2: pack value+bv -> buf1 ; proj = wq @ q (buf2) -> regs
    {
        const int ob = ww * 16 + lq * 4;
        float bias[4];
#pragma unroll
        for (int r = 0; r < 4; r++) bias[r] = bv[ob + r];
#pragma unroll
        for (int nt = 0; nt < 16; nt++) {
            const int wg = nt * 16 + lm;
            uint2 pk;
            pk.x = cvtpk(accv[nt][0] + bias[0], accv[nt][1] + bias[1]);
            pk.y = cvtpk(accv[nt][2] + bias[2], accv[nt][3] + bias[3]);
            *(uint2*)(&buf1[wg * PIT + ob]) = pk;
        }
    }
    f32x4 accp[16];
#pragma unroll
    for (int nt = 0; nt < 16; nt++) accp[nt] = (f32x4){0.f, 0.f, 0.f, 0.f};
#pragma unroll
    for (int kk = 0; kk < 4; kk++) {
        s16x8 a = *(const s16x8*)(wq_bf + (size_t)(ww * 16 + lm) * 128 + kk * 32 + lq * 8);
#pragma unroll
        for (int nt = 0; nt < 16; nt++) {
            s16x8 bfv = *(const s16x8*)(&buf2[(nt * 16 + lm) * PIT + kk * 32 + lq * 8]);
            accp[nt] = __builtin_amdgcn_mfma_f32_16x16x32_bf16(a, bfv, accp[nt], 0, 0, 0);
        }
    }
    __syncthreads();   // all q reads done; buf2 reusable for proj

    // ---- P3: pack proj+bq -> buf2
    {
        const int ob = ww * 16 + lq * 4;
        float bias[4];
#pragma unroll
        for (int r = 0; r < 4; r++) bias[r] = bq[ob + r];
#pragma unroll
        for (int nt = 0; nt < 16; nt++) {
            const int wg = nt * 16 + lm;
            uint2 pk;
            pk.x = cvtpk(accp[nt][0] + bias[0], accp[nt][1] + bias[1]);
            pk.y = cvtpk(accp[nt][2] + bias[2], accp[nt][3] + bias[3]);
            *(uint2*)(&buf2[wg * PIT + ob]) = pk;
        }
    }
    __syncthreads();

    // ---- P4: softmax + keypoints, kept in REGISTERS
    float attnr[4][8], kpr[4][8];
#pragma unroll
    for (int gi = 0; gi < 4; gi++) {
        const int g = half * 4 + gi;
        s16x8 lg = *(const s16x8*)(&buf2[px * PIT + 64 + g * 8]);
        float L[8], m = -1e30f;
#pragma unroll
        for (int j = 0; j < 8; j++) { L[j] = bf2f(lg[j]); m = fmaxf(m, L[j]); }
        float s = 0.f;
#pragma unroll
        for (int j = 0; j < 8; j++) { L[j] = fexp(L[j] - m); s += L[j]; }
        float inv = frcp(s);
#pragma unroll
        for (int j = 0; j < 8; j++) attnr[gi][j] = L[j] * inv;
#pragma unroll
        for (int p = 0; p < 4; p++) {
            size_t kidx = kbase + (size_t)(gi * 4 + p) * HW;
            float oc = bf2f(buf2[px * PIT + g * 4 + p]);
            float og = bf2f(buf2[px * PIT + 32 + g * 4 + p]);
            float ck = fminf(fmaxf(capr[gi * 4 + p] * 255.0f + oc, 0.f), 255.f);
            float gk = fminf(fmaxf(gapr[gi * 4 + p] * 255.0f + og, 0.f), 255.f);
            ckp_out[kidx] = ck;
            gkp_out[kidx] = gk;
            kpr[gi][p] = ck;
            kpr[gi][4 + p] = gk;
        }
    }
    __syncthreads();   // all proj reads done; buf2 reusable for agg

    // ---- P5: deformable sampling (value in buf1) -> agg bf16 in buf2
#pragma unroll
    for (int gi = 0; gi < 4; gi++) {
        const int g = half * 4 + gi;
        f32x2 A[8];
#pragma unroll
        for (int k = 0; k < 8; k++) A[k] = (f32x2){0.f, 0.f};
        // ctx points: gather value from buf1 (pairwise f32x2 math -> v_pk_fma)
#pragma unroll
        for (int j = 0; j < 4; j++) {
            float x = kpr[gi][j];
            float fx = floorf(x);
            int i0 = (int)fx;
            int i1 = min(i0 + 1, Ww - 1);
            float tt = x - fx;
            float c0 = attnr[gi][j] * (1.f - tt);
            float c1 = attnr[gi][j] * tt;
            f32x2 c0v = {c0, c0}, c1v = {c1, c1};
            uint4 v0a = *(const uint4*)(&buf1[i0 * PIT + g * 16]);
            uint4 v0b = *(const uint4*)(&buf1[i0 * PIT + g * 16 + 8]);
            uint4 v1a = *(const uint4*)(&buf1[i1 * PIT + g * 16]);
            uint4 v1b = *(const uint4*)(&buf1[i1 * PIT + g * 16 + 8]);
            const unsigned w0[8] = {v0a.x, v0a.y, v0a.z, v0a.w, v0b.x, v0b.y, v0b.z, v0b.w};
            const unsigned w1[8] = {v1a.x, v1a.y, v1a.z, v1a.w, v1b.x, v1b.y, v1b.z, v1b.w};
#pragma unroll
            for (int k = 0; k < 8; k++)
                A[k] += unpk(w0[k]) * c0v + unpk(w1[k]) * c1v;
        }
        // geo points via linearity: wn @ sample(geo) + bn * sum(attn_geo)
        {
            float gs0 = 0.f, gs1 = 0.f, gs2 = 0.f, as = 0.f;
#pragma unroll
            for (int j = 4; j < 8; j++) {
                float x = kpr[gi][j];
                float fx = floorf(x);
                int i0 = (int)fx;
                int i1 = min(i0 + 1, Ww - 1);
                float tt = x - fx;
                float c0 = attnr[gi][j] * (1.f - tt);
                float c1 = attnr[gi][j] * tt;
                f32x4 ga = sgeo4[i0], gb = sgeo4[i1];
                gs0 += c0 * ga[0] + c1 * gb[0];
                gs1 += c0 * ga[1] + c1 * gb[1];
                gs2 += c0 * ga[2] + c1 * gb[2];
                as  += attnr[gi][j];
            }
            f32x2 g0v = {gs0, gs0}, g1v = {gs1, gs1}, g2v = {gs2, gs2}, asv = {as, as};
#pragma unroll
            for (int k = 0; k < 8; k++) {
                const f32x2* wp = &swnp[(g * 8 + k) * 4];
                A[k] += wp[0] * g0v + wp[1] * g1v + wp[2] * g2v + wp[3] * asv;
            }
        }
        uint4 o0, o1;
        o0.x = cvtpk(A[0][0], A[0][1]); o0.y = cvtpk(A[1][0], A[1][1]);
        o0.z = cvtpk(A[2][0], A[2][1]); o0.w = cvtpk(A[3][0], A[3][1]);
        o1.x = cvtpk(A[4][0], A[4][1]); o1.y = cvtpk(A[5][0], A[5][1]);
        o1.z = cvtpk(A[6][0], A[6][1]); o1.w = cvtpk(A[7][0], A[7][1]);
        *(uint4*)(&buf2[px * PIT + g * 16])     = o0;
        *(uint4*)(&buf2[px * PIT + g * 16 + 8]) = o1;
    }
    __syncthreads();

    // ---- P6: upd = wo @ agg (buf2) ; x = q + (upd+bo)*mask -> buf1 (no inner barrier)
    {
        f32x4 acc1[16];
#pragma unroll
        for (int nt = 0; nt < 16; nt++) acc1[nt] = (f32x4){0.f, 0.f, 0.f, 0.f};
#pragma unroll
        for (int kk = 0; kk < 4; kk++) {
            s16x8 a = *(const s16x8*)(wo_bf + (size_t)(ww * 16 + lm) * 128 + kk * 32 + lq * 8);
#pragma unroll
            for (int nt = 0; nt < 16; nt++) {
                s16x8 bfv = *(const s16x8*)(&buf2[(nt * 16 + lm) * PIT + kk * 32 + lq * 8]);
                acc1[nt] = __builtin_amdgcn_mfma_f32_16x16x32_bf16(a, bfv, acc1[nt], 0, 0, 0);
            }
        }
        const int ob = ww * 16 + lq * 4;
        float bias[4];
#pragma unroll
        for (int r = 0; r < 4; r++) bias[r] = bo[ob + r];
#pragma unroll
        for (int nt = 0; nt < 16; nt++) {
            const int wg = nt * 16 + lm;
            float mval = msk[hWw + wg];
            float xv[4];
#pragma unroll
            for (int r = 0; r < 4; r++) {
                float upd = acc1[nt][r] + bias[r];
                float qv = q[(size_t)(ob + r) * HW + hWw + wg];
                xv[r] = qv + upd * mval;
            }
            uint2 pk;
            pk.x = cvtpk(xv[0], xv[1]);
            pk.y = cvtpk(xv[2], xv[3]);
            *(uint2*)(&buf1[wg * PIT + ob]) = pk;
        }
    }
    __syncthreads();

    // ---- P7: LayerNorm over channels (in place, bf16)
    {
        float ls = 0.f, lsq = 0.f;
#pragma unroll
        for (int c8 = 0; c8 < 8; c8++) {
            uint4 u = *(const uint4*)(&buf1[px * PIT + half * 64 + c8 * 8]);
            const unsigned wv4[4] = {u.x, u.y, u.z, u.w};
#pragma unroll
            for (int j2 = 0; j2 < 4; j2++) {
                f32x2 e = unpk(wv4[j2]);
                ls  += e[0] + e[1];
                lsq += e[0] * e[0] + e[1] * e[1];
            }
        }
        redS[t] = ls; redQ[t] = lsq;
        __syncthreads();
        if (t < 256) {
            float s  = redS[t] + redS[t + 256];
            float qq = redQ[t] + redQ[t + 256];
            float mu = s * (1.f / 128.f);
            float var = qq * (1.f / 128.f) - mu * mu;
            smu[t] = mu;
            srs[t] = __builtin_amdgcn_rsqf(var + 1e-5f);
        }
        __syncthreads();
        const float mu = smu[px], rs = srs[px];
#pragma unroll
        for (int c8 = 0; c8 < 8; c8++) {
            const int cb = half * 64 + c8 * 8;
            uint4 u = *(const uint4*)(&buf1[px * PIT + cb]);
            const unsigned wv4[4] = {u.x, u.y, u.z, u.w};
            uint4 o;
            unsigned res[4];
#pragma unroll
            for (int j2 = 0; j2 < 4; j2++) {
                f32x2 e = unpk(wv4[j2]);
                const int c = cb + j2 * 2;
                float a0 = rs * sln[c],     bb0 = sln[128 + c]     - mu * a0;
                float a1 = rs * sln[c + 1], bb1 = sln[128 + c + 1] - mu * a1;
                res[j2] = cvtpk(e[0] * a0 + bb0, e[1] * a1 + bb1);
            }
            o.x = res[0]; o.y = res[1]; o.z = res[2]; o.w = res[3];
            *(uint4*)(&buf1[px * PIT + cb]) = o;
        }
    }
    __syncthreads();

    // ---- P8: FFN, two 128-col hidden passes; acc3 accumulates
    f32x4 acc3[16];
#pragma unroll
    for (int nt = 0; nt < 16; nt++) acc3[nt] = (f32x4){0.f, 0.f, 0.f, 0.f};

    for (int jc = 0; jc < 2; jc++) {
        f32x4 acc2[16];
#pragma unroll
        for (int nt = 0; nt < 16; nt++) acc2[nt] = (f32x4){0.f, 0.f, 0.f, 0.f};
#pragma unroll
        for (int kk = 0; kk < 4; kk++) {
            s16x8 a = *(const s16x8*)(w1_bf + (size_t)(jc * 128 + ww * 16 + lm) * 128 + kk * 32 + lq * 8);
#pragma unroll
            for (int nt = 0; nt < 16; nt++) {
                s16x8 bfv = *(const s16x8*)(&buf1[(nt * 16 + lm) * PIT + kk * 32 + lq * 8]);
                acc2[nt] = __builtin_amdgcn_mfma_f32_16x16x32_bf16(a, bfv, acc2[nt], 0, 0, 0);
            }
        }
        {
            const int jb = ww * 16 + lq * 4;
            float bias[4];
#pragma unroll
            for (int r = 0; r < 4; r++) bias[r] = b1[jc * 128 + jb + r];
#pragma unroll
            for (int nt = 0; nt < 16; nt++) {
                const int wg = nt * 16 + lm;
                float o[4];
#pragma unroll
                for (int r = 0; r < 4; r++) {
                    float hv = acc2[nt][r] + bias[r];
                    o[r] = hv * frcp(1.f + fexp(-hv));   // silu, fast sigmoid
                }
                uint2 pk;
                pk.x = cvtpk(o[0], o[1]);
                pk.y = cvtpk(o[2], o[3]);
                *(uint2*)(&buf2[wg * PIT + jb]) = pk;
            }
        }
        __syncthreads();
#pragma unroll
        for (int kk = 0; kk < 4; kk++) {
            s16x8 a = *(const s16x8*)(w2_bf + (size_t)(ww * 16 + lm) * 256 + jc * 128 + kk * 32 + lq * 8);
#pragma unroll
            for (int nt = 0; nt < 16; nt++) {
                s16x8 bfv = *(const s16x8*)(&buf2[(nt * 16 + lm) * PIT + kk * 32 + lq * 8]);
                acc3[nt] = __builtin_amdgcn_mfma_f32_16x16x32_bf16(a, bfv, acc3[nt], 0, 0, 0);
            }
        }
        __syncthreads();
    }

    // ---- store: y = xn + b2 + ffn
    {
        const int ob = ww * 16 + lq * 4;
        float b2v[4];
#pragma unroll
        for (int r = 0; r < 4; r++) b2v[r] = b2[ob + r];
#pragma unroll
        for (int nt = 0; nt < 16; nt++) {
            const int wg = nt * 16 + lm;
            s16x4 xn4 = *(const s16x4*)(&buf1[wg * PIT + ob]);
#pragma unroll
            for (int r = 0; r < 4; r++)
                outp[(size_t)(ob + r) * HW + hWw + wg] = bf2f(xn4[r]) + b2v[r] + acc3[nt][r];
        }
    }
}

// ---------------------------------------------------------------------------
extern "C" void kernel_launch(void* const* d_in, const int* in_sizes, int n_in,
                              void* d_out, int out_size, void* d_ws, size_t ws_size,
                              hipStream_t stream)
{
    const float* match_l = (const float*)d_in[0];
    const float* match_r = (const float*)d_in[1];
    const float* feat_l  = (const float*)d_in[2];
    const float* feat_r  = (const float*)d_in[3];
    const float* norm_l  = (const float*)d_in[4];
    const float* norm_r  = (const float*)d_in[5];
    const float* gml     = (const float*)d_in[6];
    const float* gmr     = (const float*)d_in[7];
    const float* cap     = (const float*)d_in[8];
    const float* gap     = (const float*)d_in[9];
    const float* wv  = (const float*)d_in[10]; const float* bv  = (const float*)d_in[11];
    const float* wn  = (const float*)d_in[12]; const float* bn  = (const float*)d_in[13];
    const float* woc = (const float*)d_in[14]; const float* boc = (const float*)d_in[15];
    const float* wog = (const float*)d_in[16]; const float* bog = (const float*)d_in[17];
    const float* wa  = (const float*)d_in[18]; const float* ba  = (const float*)d_in[19];
    const float* wo  = (const float*)d_in[20]; const float* bo  = (const float*)d_in[21];
    const float* lnw = (const float*)d_in[22]; const float* lnb = (const float*)d_in[23];
    const float* w1  = (const float*)d_in[24]; const float* b1  = (const float*)d_in[25];
    const float* w2  = (const float*)d_in[26]; const float* b2  = (const float*)d_in[27];

    float* out = (float*)d_out;
    float* out_ml  = out;
    float* out_mr  = out + (size_t)2 * CHW;
    float* ckp_out = out + (size_t)4 * CHW;
    float* gkp_out = ckp_out + (size_t)B2v * Gg * Pp * HW;

    float* ws = (float*)d_ws;
    float* bq  = ws;                       // 128 f32
    short* wbf = (short*)(bq + 128);       // 114688 bf16

    prep_kernel<<<dim3(449), dim3(256), 0, stream>>>(
        wv, woc, wog, wa, wo, w1, w2, boc, bog, ba, wbf, bq);
    mega_kernel<<<dim3(Hh, B2v), dim3(512), 0, stream>>>(
        match_l, match_r, feat_l, feat_r, norm_l, norm_r, gml, gmr, cap, gap,
        wbf, bq, bv, wn, bn, bo, lnw, lnb, b1, b2,
        out_ml, out_mr, ckp_out, gkp_out);
}